// Round 1
// baseline (67.129 us; speedup 1.0000x reference)
//
#include <hip/hip_runtime.h>

// Fused e3nn TensorProduct(uvuv, component-norm) + per-sample o3.Linear.
// x:[B,288]=32x0e+32x1o+32x2e, y:[B,9]=1x0e+1x1o+1x2e, weight:[B,11264], out:[B,288].
//
// Only TP paths whose (l,p) matches the output irreps contribute:
//   l3=0: (0,0,0) (1,1,0) (2,2,0)            -> U=96,  w offset 0    (f4 0)
//   l3=1: (0,1,1) (1,0,1) (1,2,1) (2,1,1)    -> U=128, w offset 3072 (f4 768)
//   l3=2: (0,2,2) (1,1,2) (2,0,2) (2,2,2)    -> U=128, w offset 7168 (f4 1792)
// w[b,u,o] = weight[b, off + u*32 + o];  out_l[b,o,k] = (1/sqrt(U)) * sum_u w*z[u,k].
//
// Real Wigner-3j constants derived from the reference's exact construction
// (Condon-Shortley CG + e3nn Q change-of-basis; all path sums l1+l2+l3 even ->
// primary branch, tensors = positively-normalized Gaunt coefficients).
// l=1 real basis order: (y, z, x).  l=2: (xy, yz, z2, xz, x2-y2).

using f4 = float __attribute__((ext_vector_type(4)));

__global__ __launch_bounds__(256) void etp_fused(
    const float* __restrict__ xg,
    const float* __restrict__ yg,
    const float* __restrict__ wg,
    float* __restrict__ outg)
{
    const int b = blockIdx.x;
    const int t = threadIdx.x;

    __shared__ __align__(16) float xs[288];
    __shared__ float ys[9];
    __shared__ float z0s[96];
    __shared__ float z1s[384];        // [u][k], k=0..2
    __shared__ float z2s[640];        // [u][k], k=0..4
    __shared__ float red[160 * 33];   // [o*K+k][33] reduction scratch (stride 33: <=2-way banks)
    __shared__ __align__(16) float orow[288];

    // ---- stage x (float4) and y ----
    if (t < 72) {
        reinterpret_cast<f4*>(xs)[t] = reinterpret_cast<const f4*>(xg)[(size_t)b * 72 + t];
    } else if (t < 81) {
        ys[t - 72] = yg[(size_t)b * 9 + (t - 72)];
    }
    __syncthreads();

    const float y0 = ys[0];
    const float ya = ys[1], yb = ys[2], yc = ys[3];                     // y1 = (y,z,x)
    const float Y0 = ys[4], Y1 = ys[5], Y2 = ys[6], Y3 = ys[7], Y4 = ys[8]; // y2

    // sqrt(2l3+1)-scaled w3j constants
    constexpr float S3  = 0.5477225575051661f;  // sqrt(3)*1/sqrt(10)
    constexpr float D3  = 0.31622776601683794f; // sqrt(3)*1/sqrt(30)
    constexpr float TD3 = 0.6324555320336759f;  // sqrt(3)*2/sqrt(30)
    constexpr float S5  = 0.7071067811865476f;  // sqrt(5)*1/sqrt(10)
    constexpr float D5  = 0.4082482904638631f;  // sqrt(5)*1/sqrt(30)
    constexpr float P5  = 0.5345224838248488f;  // sqrt(5)*2/sqrt(70)
    constexpr float Q5  = 0.2672612419124244f;  // sqrt(5)*1/sqrt(70)
    constexpr float R5  = 0.4629100498862757f;  // sqrt(5)*sqrt(3/70)
    constexpr float N3  = 0.5773502691896258f;  // 1/sqrt(3)   (1,1,0)
    constexpr float N5  = 0.4472135954999579f;  // 1/sqrt(5)   (2,2,0)

    // ---- compute z (TP intermediate), threads split: t<128 -> z1 row, t>=128 -> z2 row ----
    if (t < 128) {
        const int u = t;
        float o0, o1, o2;
        if (u < 32) {                       // (0,1,1): x0*y1
            const float s = xs[u];
            o0 = s * ya; o1 = s * yb; o2 = s * yc;
        } else if (u < 64) {                // (1,0,1): x1*y0
            const float* p = &xs[32 + 3 * (u - 32)];
            o0 = p[0] * y0; o1 = p[1] * y0; o2 = p[2] * y0;
        } else if (u < 96) {                // (1,2,1)
            const float* p = &xs[32 + 3 * (u - 64)];
            const float a = p[0], bz = p[1], cx = p[2];
            o0 = S3 * (cx * Y0 + bz * Y1 - a * Y4) - D3 * a * Y2;
            o1 = S3 * (a * Y1 + cx * Y3) + TD3 * bz * Y2;
            o2 = S3 * (a * Y0 + bz * Y3 + cx * Y4) - D3 * cx * Y2;
        } else {                            // (2,1,1)
            const float* p = &xs[128 + 5 * (u - 96)];
            const float X0 = p[0], X1 = p[1], X2 = p[2], X3 = p[3], X4 = p[4];
            o0 = S3 * (yc * X0 + yb * X1 - ya * X4) - D3 * ya * X2;
            o1 = S3 * (ya * X1 + yc * X3) + TD3 * yb * X2;
            o2 = S3 * (ya * X0 + yb * X3 + yc * X4) - D3 * yc * X2;
        }
        z1s[3 * u] = o0; z1s[3 * u + 1] = o1; z1s[3 * u + 2] = o2;
    } else {
        const int u = t - 128;
        float c0, c1, c2, c3, c4;
        if (u < 32) {                       // (0,2,2): x0*y2
            const float s = xs[u];
            c0 = s * Y0; c1 = s * Y1; c2 = s * Y2; c3 = s * Y3; c4 = s * Y4;
        } else if (u < 64) {                // (1,1,2)
            const float* p = &xs[32 + 3 * (u - 32)];
            const float a = p[0], bz = p[1], cx = p[2];
            c0 = S5 * (a * yc + cx * ya);
            c1 = S5 * (a * yb + bz * ya);
            c2 = D5 * (2.0f * bz * yb - a * ya - cx * yc);
            c3 = S5 * (cx * yb + bz * yc);
            c4 = S5 * (cx * yc - a * ya);
        } else if (u < 96) {                // (2,0,2): x2*y0
            const float* p = &xs[128 + 5 * (u - 64)];
            c0 = p[0] * y0; c1 = p[1] * y0; c2 = p[2] * y0; c3 = p[3] * y0; c4 = p[4] * y0;
        } else {                            // (2,2,2)
            const float* p = &xs[128 + 5 * (u - 96)];
            const float X0 = p[0], X1 = p[1], X2 = p[2], X3 = p[3], X4 = p[4];
            c0 = -P5 * (X0 * Y2 + X2 * Y0) + R5 * (X1 * Y3 + X3 * Y1);
            c1 =  Q5 * (X1 * Y2 + X2 * Y1) - R5 * (X1 * Y4 + X4 * Y1) + R5 * (X0 * Y3 + X3 * Y0);
            c2 =  P5 * (X2 * Y2 - X0 * Y0 - X4 * Y4) + Q5 * (X1 * Y1 + X3 * Y3);
            c3 =  Q5 * (X3 * Y2 + X2 * Y3) + R5 * (X3 * Y4 + X4 * Y3) + R5 * (X0 * Y1 + X1 * Y0);
            c4 = -P5 * (X4 * Y2 + X2 * Y4) + R5 * (X3 * Y3 - X1 * Y1);
        }
        float* zp = &z2s[5 * u];
        zp[0] = c0; zp[1] = c1; zp[2] = c2; zp[3] = c3; zp[4] = c4;
    }
    if (t < 96) {                           // z0: (0,0,0),(1,1,0),(2,2,0)
        float v;
        if (t < 32) {
            v = xs[t] * y0;
        } else if (t < 64) {
            const float* p = &xs[32 + 3 * (t - 32)];
            v = N3 * (p[0] * ya + p[1] * yb + p[2] * yc);
        } else {
            const float* p = &xs[128 + 5 * (t - 64)];
            v = N5 * (p[0] * Y0 + p[1] * Y1 + p[2] * Y2 + p[3] * Y3 + p[4] * Y4);
        }
        z0s[t] = v;
    }
    __syncthreads();

    // ---- stream weight (float4, nontemporal; per-wave 1KiB-contiguous) ----
    const int oq = t & 7;       // float4 column group: outputs o = 4*oq .. 4*oq+3
    const int ug = t >> 3;      // u residue class: u = i*32 + ug
    const f4* w4 = reinterpret_cast<const f4*>(wg) + (size_t)b * 2816;

    f4 a0 = {0.f, 0.f, 0.f, 0.f};
#pragma unroll
    for (int i = 0; i < 3; ++i) {
        const int u = i * 32 + ug;
        const f4 wv = __builtin_nontemporal_load(&w4[u * 8 + oq]);
        a0 += wv * z0s[u];
    }
    f4 a1k0 = {0,0,0,0}, a1k1 = {0,0,0,0}, a1k2 = {0,0,0,0};
#pragma unroll
    for (int i = 0; i < 4; ++i) {
        const int u = i * 32 + ug;
        const f4 wv = __builtin_nontemporal_load(&w4[768 + u * 8 + oq]);
        a1k0 += wv * z1s[3 * u];
        a1k1 += wv * z1s[3 * u + 1];
        a1k2 += wv * z1s[3 * u + 2];
    }
    f4 a2k0 = {0,0,0,0}, a2k1 = {0,0,0,0}, a2k2 = {0,0,0,0}, a2k3 = {0,0,0,0}, a2k4 = {0,0,0,0};
#pragma unroll
    for (int i = 0; i < 4; ++i) {
        const int u = i * 32 + ug;
        const f4 wv = __builtin_nontemporal_load(&w4[1792 + u * 8 + oq]);
        a2k0 += wv * z2s[5 * u];
        a2k1 += wv * z2s[5 * u + 1];
        a2k2 += wv * z2s[5 * u + 2];
        a2k3 += wv * z2s[5 * u + 3];
        a2k4 += wv * z2s[5 * u + 4];
    }

    const int o = oq * 4;

    // ---- reduce l=0 (32 outputs) ----
    red[(o + 0) * 33 + ug] = a0.x;
    red[(o + 1) * 33 + ug] = a0.y;
    red[(o + 2) * 33 + ug] = a0.z;
    red[(o + 3) * 33 + ug] = a0.w;
    __syncthreads();
    if (t < 32) {
        float s = 0.f;
#pragma unroll
        for (int g = 0; g < 32; ++g) s += red[t * 33 + g];
        orow[t] = 0.10206207261596575f * s;   // 1/sqrt(96)
    }
    __syncthreads();

    // ---- reduce l=1 (96 outputs: o*3+k) ----
    red[((o + 0) * 3 + 0) * 33 + ug] = a1k0.x;
    red[((o + 1) * 3 + 0) * 33 + ug] = a1k0.y;
    red[((o + 2) * 3 + 0) * 33 + ug] = a1k0.z;
    red[((o + 3) * 3 + 0) * 33 + ug] = a1k0.w;
    red[((o + 0) * 3 + 1) * 33 + ug] = a1k1.x;
    red[((o + 1) * 3 + 1) * 33 + ug] = a1k1.y;
    red[((o + 2) * 3 + 1) * 33 + ug] = a1k1.z;
    red[((o + 3) * 3 + 1) * 33 + ug] = a1k1.w;
    red[((o + 0) * 3 + 2) * 33 + ug] = a1k2.x;
    red[((o + 1) * 3 + 2) * 33 + ug] = a1k2.y;
    red[((o + 2) * 3 + 2) * 33 + ug] = a1k2.z;
    red[((o + 3) * 3 + 2) * 33 + ug] = a1k2.w;
    __syncthreads();
    if (t < 96) {
        float s = 0.f;
#pragma unroll
        for (int g = 0; g < 32; ++g) s += red[t * 33 + g];
        orow[32 + t] = 0.08838834764831845f * s;  // 1/sqrt(128)
    }
    __syncthreads();

    // ---- reduce l=2 (160 outputs: o*5+k) ----
    red[((o + 0) * 5 + 0) * 33 + ug] = a2k0.x;
    red[((o + 1) * 5 + 0) * 33 + ug] = a2k0.y;
    red[((o + 2) * 5 + 0) * 33 + ug] = a2k0.z;
    red[((o + 3) * 5 + 0) * 33 + ug] = a2k0.w;
    red[((o + 0) * 5 + 1) * 33 + ug] = a2k1.x;
    red[((o + 1) * 5 + 1) * 33 + ug] = a2k1.y;
    red[((o + 2) * 5 + 1) * 33 + ug] = a2k1.z;
    red[((o + 3) * 5 + 1) * 33 + ug] = a2k1.w;
    red[((o + 0) * 5 + 2) * 33 + ug] = a2k2.x;
    red[((o + 1) * 5 + 2) * 33 + ug] = a2k2.y;
    red[((o + 2) * 5 + 2) * 33 + ug] = a2k2.z;
    red[((o + 3) * 5 + 2) * 33 + ug] = a2k2.w;
    red[((o + 0) * 5 + 3) * 33 + ug] = a2k3.x;
    red[((o + 1) * 5 + 3) * 33 + ug] = a2k3.y;
    red[((o + 2) * 5 + 3) * 33 + ug] = a2k3.z;
    red[((o + 3) * 5 + 3) * 33 + ug] = a2k3.w;
    red[((o + 0) * 5 + 4) * 33 + ug] = a2k4.x;
    red[((o + 1) * 5 + 4) * 33 + ug] = a2k4.y;
    red[((o + 2) * 5 + 4) * 33 + ug] = a2k4.z;
    red[((o + 3) * 5 + 4) * 33 + ug] = a2k4.w;
    __syncthreads();
    if (t < 160) {
        float s = 0.f;
#pragma unroll
        for (int g = 0; g < 32; ++g) s += red[t * 33 + g];
        orow[128 + t] = 0.08838834764831845f * s; // 1/sqrt(128)
    }
    __syncthreads();

    // ---- coalesced float4 output write ----
    if (t < 72) {
        reinterpret_cast<f4*>(outg)[(size_t)b * 72 + t] =
            reinterpret_cast<const f4*>(orow)[t];
    }
}

extern "C" void kernel_launch(void* const* d_in, const int* in_sizes, int n_in,
                              void* d_out, int out_size, void* d_ws, size_t ws_size,
                              hipStream_t stream) {
    const float* x = (const float*)d_in[0];
    const float* y = (const float*)d_in[1];
    const float* w = (const float*)d_in[2];
    float* out = (float*)d_out;
    const int rows = in_sizes[0] / 288;   // 8192
    etp_fused<<<rows, 256, 0, stream>>>(x, y, w, out);
}

// Round 2
// 66.005 us; speedup vs baseline: 1.0170x; 1.0170x over previous
//
#include <hip/hip_runtime.h>

// Fused e3nn TensorProduct(uvuv, component-norm) + per-sample o3.Linear.
// x:[B,288]=32x0e+32x1o+32x2e, y:[B,9]=1x0e+1x1o+1x2e, weight:[B,11264], out:[B,288].
//
// Contributing TP paths (match output irreps):
//   l3=0: (0,0,0) (1,1,0) (2,2,0)            -> U=96,  w f4-offset 0
//   l3=1: (0,1,1) (1,0,1) (1,2,1) (2,1,1)    -> U=128, w f4-offset 768
//   l3=2: (0,2,2) (1,1,2) (2,0,2) (2,2,2)    -> U=128, w f4-offset 1792
//
// R2 changes vs R1 (verified-correct math unchanged):
//  - weight loads issued BEFORE the z-compute barriers (latency overlaps z phase)
//  - reduction: shfl_xor(8/16/32) in-wave (8 ug partials) -> one LDS phase of
//    4 wave-partials per output -> single barrier -> direct f4 global store

using f4 = float __attribute__((ext_vector_type(4)));

__device__ inline f4 wred8(f4 v) {
    // reduce over lanes differing in bits 3..5 (the 8 ug values in this wave);
    // lane&7 (= oq) is preserved by the xor masks.
#pragma unroll
    for (int m = 8; m <= 32; m <<= 1) {
        v.x += __shfl_xor(v.x, m);
        v.y += __shfl_xor(v.y, m);
        v.z += __shfl_xor(v.z, m);
        v.w += __shfl_xor(v.w, m);
    }
    return v;
}

__global__ __launch_bounds__(256) void etp_fused(
    const float* __restrict__ xg,
    const float* __restrict__ yg,
    const float* __restrict__ wg,
    float* __restrict__ outg)
{
    const int b = blockIdx.x;
    const int t = threadIdx.x;

    __shared__ __align__(16) float xs[288];
    __shared__ float ys[9];
    __shared__ float z0s[96];
    __shared__ float z1s[384];        // [u][k], k=0..2
    __shared__ float z2s[640];        // [u][k], k=0..4
    __shared__ float red[288 * 5];    // [out_idx][wave] wave-partials (stride 5)

    // ---- stage x (float4) and y ----
    if (t < 72) {
        reinterpret_cast<f4*>(xs)[t] =
            __builtin_nontemporal_load(reinterpret_cast<const f4*>(xg) + (size_t)b * 72 + t);
    } else if (t < 81) {
        ys[t - 72] = yg[(size_t)b * 9 + (t - 72)];
    }

    // ---- prefetch ALL weight data now (independent of LDS / barriers) ----
    const int oq = t & 7;       // float4 column group: outputs o = 4*oq .. 4*oq+3
    const int ug = t >> 3;      // u residue class: u = i*32 + ug
    const f4* w4 = reinterpret_cast<const f4*>(wg) + (size_t)b * 2816;

    f4 wa0 = __builtin_nontemporal_load(&w4[(0 * 32 + ug) * 8 + oq]);
    f4 wa1 = __builtin_nontemporal_load(&w4[(1 * 32 + ug) * 8 + oq]);
    f4 wa2 = __builtin_nontemporal_load(&w4[(2 * 32 + ug) * 8 + oq]);
    f4 wb0 = __builtin_nontemporal_load(&w4[768 + (0 * 32 + ug) * 8 + oq]);
    f4 wb1 = __builtin_nontemporal_load(&w4[768 + (1 * 32 + ug) * 8 + oq]);
    f4 wb2 = __builtin_nontemporal_load(&w4[768 + (2 * 32 + ug) * 8 + oq]);
    f4 wb3 = __builtin_nontemporal_load(&w4[768 + (3 * 32 + ug) * 8 + oq]);
    f4 wc0 = __builtin_nontemporal_load(&w4[1792 + (0 * 32 + ug) * 8 + oq]);
    f4 wc1 = __builtin_nontemporal_load(&w4[1792 + (1 * 32 + ug) * 8 + oq]);
    f4 wc2 = __builtin_nontemporal_load(&w4[1792 + (2 * 32 + ug) * 8 + oq]);
    f4 wc3 = __builtin_nontemporal_load(&w4[1792 + (3 * 32 + ug) * 8 + oq]);

    __syncthreads();

    const float y0 = ys[0];
    const float ya = ys[1], yb = ys[2], yc = ys[3];                         // y1 = (y,z,x)
    const float Y0 = ys[4], Y1 = ys[5], Y2 = ys[6], Y3 = ys[7], Y4 = ys[8]; // y2

    // sqrt(2l3+1)-scaled w3j constants
    constexpr float S3  = 0.5477225575051661f;
    constexpr float D3  = 0.31622776601683794f;
    constexpr float TD3 = 0.6324555320336759f;
    constexpr float S5  = 0.7071067811865476f;
    constexpr float D5  = 0.4082482904638631f;
    constexpr float P5  = 0.5345224838248488f;
    constexpr float Q5  = 0.2672612419124244f;
    constexpr float R5  = 0.4629100498862757f;
    constexpr float N3  = 0.5773502691896258f;
    constexpr float N5  = 0.4472135954999579f;

    // ---- compute z (TP intermediate) ----
    if (t < 128) {
        const int u = t;
        float o0, o1, o2;
        if (u < 32) {                       // (0,1,1): x0*y1
            const float s = xs[u];
            o0 = s * ya; o1 = s * yb; o2 = s * yc;
        } else if (u < 64) {                // (1,0,1): x1*y0
            const float* p = &xs[32 + 3 * (u - 32)];
            o0 = p[0] * y0; o1 = p[1] * y0; o2 = p[2] * y0;
        } else if (u < 96) {                // (1,2,1)
            const float* p = &xs[32 + 3 * (u - 64)];
            const float a = p[0], bz = p[1], cx = p[2];
            o0 = S3 * (cx * Y0 + bz * Y1 - a * Y4) - D3 * a * Y2;
            o1 = S3 * (a * Y1 + cx * Y3) + TD3 * bz * Y2;
            o2 = S3 * (a * Y0 + bz * Y3 + cx * Y4) - D3 * cx * Y2;
        } else {                            // (2,1,1)
            const float* p = &xs[128 + 5 * (u - 96)];
            const float X0 = p[0], X1 = p[1], X2 = p[2], X3 = p[3], X4 = p[4];
            o0 = S3 * (yc * X0 + yb * X1 - ya * X4) - D3 * ya * X2;
            o1 = S3 * (ya * X1 + yc * X3) + TD3 * yb * X2;
            o2 = S3 * (ya * X0 + yb * X3 + yc * X4) - D3 * yc * X2;
        }
        z1s[3 * u] = o0; z1s[3 * u + 1] = o1; z1s[3 * u + 2] = o2;
    } else {
        const int u = t - 128;
        float c0, c1, c2, c3, c4;
        if (u < 32) {                       // (0,2,2): x0*y2
            const float s = xs[u];
            c0 = s * Y0; c1 = s * Y1; c2 = s * Y2; c3 = s * Y3; c4 = s * Y4;
        } else if (u < 64) {                // (1,1,2)
            const float* p = &xs[32 + 3 * (u - 32)];
            const float a = p[0], bz = p[1], cx = p[2];
            c0 = S5 * (a * yc + cx * ya);
            c1 = S5 * (a * yb + bz * ya);
            c2 = D5 * (2.0f * bz * yb - a * ya - cx * yc);
            c3 = S5 * (cx * yb + bz * yc);
            c4 = S5 * (cx * yc - a * ya);
        } else if (u < 96) {                // (2,0,2): x2*y0
            const float* p = &xs[128 + 5 * (u - 64)];
            c0 = p[0] * y0; c1 = p[1] * y0; c2 = p[2] * y0; c3 = p[3] * y0; c4 = p[4] * y0;
        } else {                            // (2,2,2)
            const float* p = &xs[128 + 5 * (u - 96)];
            const float X0 = p[0], X1 = p[1], X2 = p[2], X3 = p[3], X4 = p[4];
            c0 = -P5 * (X0 * Y2 + X2 * Y0) + R5 * (X1 * Y3 + X3 * Y1);
            c1 =  Q5 * (X1 * Y2 + X2 * Y1) - R5 * (X1 * Y4 + X4 * Y1) + R5 * (X0 * Y3 + X3 * Y0);
            c2 =  P5 * (X2 * Y2 - X0 * Y0 - X4 * Y4) + Q5 * (X1 * Y1 + X3 * Y3);
            c3 =  Q5 * (X3 * Y2 + X2 * Y3) + R5 * (X3 * Y4 + X4 * Y3) + R5 * (X0 * Y1 + X1 * Y0);
            c4 = -P5 * (X4 * Y2 + X2 * Y4) + R5 * (X3 * Y3 - X1 * Y1);
        }
        float* zp = &z2s[5 * u];
        zp[0] = c0; zp[1] = c1; zp[2] = c2; zp[3] = c3; zp[4] = c4;
    }
    if (t < 96) {                           // z0: (0,0,0),(1,1,0),(2,2,0)
        float v;
        if (t < 32) {
            v = xs[t] * y0;
        } else if (t < 64) {
            const float* p = &xs[32 + 3 * (t - 32)];
            v = N3 * (p[0] * ya + p[1] * yb + p[2] * yc);
        } else {
            const float* p = &xs[128 + 5 * (t - 64)];
            v = N5 * (p[0] * Y0 + p[1] * Y1 + p[2] * Y2 + p[3] * Y3 + p[4] * Y4);
        }
        z0s[t] = v;
    }
    __syncthreads();

    // ---- consume prefetched weights against z from LDS ----
    f4 a0   = wa0 * z0s[ug] + wa1 * z0s[32 + ug] + wa2 * z0s[64 + ug];

    f4 a1k0 = {0,0,0,0}, a1k1 = {0,0,0,0}, a1k2 = {0,0,0,0};
    {
        const f4 w0 = wb0, w1 = wb1, w2 = wb2, w3 = wb3;
        const int u0 = ug, u1 = 32 + ug, u2 = 64 + ug, u3 = 96 + ug;
        a1k0 = w0 * z1s[3*u0]   + w1 * z1s[3*u1]   + w2 * z1s[3*u2]   + w3 * z1s[3*u3];
        a1k1 = w0 * z1s[3*u0+1] + w1 * z1s[3*u1+1] + w2 * z1s[3*u2+1] + w3 * z1s[3*u3+1];
        a1k2 = w0 * z1s[3*u0+2] + w1 * z1s[3*u1+2] + w2 * z1s[3*u2+2] + w3 * z1s[3*u3+2];
    }
    f4 a2k0, a2k1, a2k2, a2k3, a2k4;
    {
        const f4 w0 = wc0, w1 = wc1, w2 = wc2, w3 = wc3;
        const int u0 = ug, u1 = 32 + ug, u2 = 64 + ug, u3 = 96 + ug;
        a2k0 = w0 * z2s[5*u0]   + w1 * z2s[5*u1]   + w2 * z2s[5*u2]   + w3 * z2s[5*u3];
        a2k1 = w0 * z2s[5*u0+1] + w1 * z2s[5*u1+1] + w2 * z2s[5*u2+1] + w3 * z2s[5*u3+1];
        a2k2 = w0 * z2s[5*u0+2] + w1 * z2s[5*u1+2] + w2 * z2s[5*u2+2] + w3 * z2s[5*u3+2];
        a2k3 = w0 * z2s[5*u0+3] + w1 * z2s[5*u1+3] + w2 * z2s[5*u2+3] + w3 * z2s[5*u3+3];
        a2k4 = w0 * z2s[5*u0+4] + w1 * z2s[5*u1+4] + w2 * z2s[5*u2+4] + w3 * z2s[5*u3+4];
    }

    // ---- in-wave reduction over the 8 ug values resident in this wave ----
    a0   = wred8(a0);
    a1k0 = wred8(a1k0); a1k1 = wred8(a1k1); a1k2 = wred8(a1k2);
    a2k0 = wred8(a2k0); a2k1 = wred8(a2k1); a2k2 = wred8(a2k2);
    a2k3 = wred8(a2k3); a2k4 = wred8(a2k4);

    // ---- one representative lane per (wave, oq) writes 36 wave-partials ----
    const int lane = t & 63;
    const int wv   = t >> 6;
    if ((lane >> 3) == 0) {               // lanes 0..7 of each wave; oq == lane
        const int o = lane * 4;
#pragma unroll
        for (int j = 0; j < 4; ++j) {
            red[(o + j) * 5 + wv]                       = a0[j];
            red[(32 + (o + j) * 3 + 0) * 5 + wv]        = a1k0[j];
            red[(32 + (o + j) * 3 + 1) * 5 + wv]        = a1k1[j];
            red[(32 + (o + j) * 3 + 2) * 5 + wv]        = a1k2[j];
            red[(128 + (o + j) * 5 + 0) * 5 + wv]       = a2k0[j];
            red[(128 + (o + j) * 5 + 1) * 5 + wv]       = a2k1[j];
            red[(128 + (o + j) * 5 + 2) * 5 + wv]       = a2k2[j];
            red[(128 + (o + j) * 5 + 3) * 5 + wv]       = a2k3[j];
            red[(128 + (o + j) * 5 + 4) * 5 + wv]       = a2k4[j];
        }
    }
    __syncthreads();

    // ---- final cross-wave sum (4 partials) + scale + direct f4 store ----
    if (t < 72) {
        const float scale = (t < 8) ? 0.10206207261596575f   // 1/sqrt(96)
                                    : 0.08838834764831845f;  // 1/sqrt(128)
        f4 r;
#pragma unroll
        for (int j = 0; j < 4; ++j) {
            const int idx = 4 * t + j;
            r[j] = (red[idx * 5 + 0] + red[idx * 5 + 1] +
                    red[idx * 5 + 2] + red[idx * 5 + 3]) * scale;
        }
        __builtin_nontemporal_store(r, reinterpret_cast<f4*>(outg) + (size_t)b * 72 + t);
    }
}

extern "C" void kernel_launch(void* const* d_in, const int* in_sizes, int n_in,
                              void* d_out, int out_size, void* d_ws, size_t ws_size,
                              hipStream_t stream) {
    const float* x = (const float*)d_in[0];
    const float* y = (const float*)d_in[1];
    const float* w = (const float*)d_in[2];
    float* out = (float*)d_out;
    const int rows = in_sizes[0] / 288;   // 8192
    etp_fused<<<rows, 256, 0, stream>>>(x, y, w, out);
}